// Round 18
// baseline (698.251 us; speedup 1.0000x reference)
//
#include <hip/hip_runtime.h>
#include <hip/hip_bf16.h>

#define B_ 32
#define S_ 512
#define W_ 20
#define T_ 16
#define E_ 300
#define H_ 128
#define M_ (B_*S_)   // 16384

typedef float f32x4 __attribute__((ext_vector_type(4)));

// workspace offsets (floats)
#define OFF_GX        0ul          // [M,768]   (dead after GRU -> reused by SRPART)
#define OFF_X         12582912ul   // [M,300]   (dead after gx GEMM -> reused by CTX)
#define OFF_SENT      17498112ul   // [M,256]
#define OFF_LASTF     21692416ul   // [32,128]
#define OFF_LASTB     21696512ul   // [32,128]
#define OFF_DOCVEC    21700608ul   // [32,256]
#define OFF_TOPICMAT  21708800ul   // [32,16,256]
#define OFF_DOCPART   21839872ul   // [32,512]
#define OFF_TOPICPART 21856256ul   // [32,16,512]
#define OFF_SEG       22118400ul   // [M] int
#define OFF_WTIH      22134784ul   // [300,768]
#define OFF_BIASIH    22365184ul   // [768]
#define OFF_W1T       22365952ul   // [512,128]
#define OFF_SRPART    0ul          // overlay GX: [M,512]
#define OFF_CTX       OFF_X        // overlay X:  [M,256]

// ---------------- fused embed_mean (blocks 0..4095) + prep (4096..4995) ----------------
__global__ __launch_bounds__(256) void embed_prep_kernel(
    const int* __restrict__ wid, const float* __restrict__ emb, float* __restrict__ x,
    const float* __restrict__ Wih_f, const float* __restrict__ Wih_b,
    const float* __restrict__ bih_f, const float* __restrict__ bih_b,
    const float* __restrict__ W1,
    float* __restrict__ Wt_ih, float* __restrict__ bias_ih, float* __restrict__ W1t) {
  int blk = blockIdx.x;
  if (blk < 4096) {
    // embed mean: wave per sentence, float4 loads
    int m = blk * 4 + (threadIdx.x >> 6);
    int lane = threadIdx.x & 63;
    const int* ids = wid + (size_t)m * W_;
    f32x4 s1 = {0.f, 0.f, 0.f, 0.f}, s2 = {0.f, 0.f, 0.f, 0.f};
    for (int w = 0; w < W_; w++) {
      const f32x4* row = (const f32x4*)(emb + (size_t)ids[w] * E_);  // 75 float4
      s1 += row[lane];
      if (lane < 11) s2 += row[64 + lane];
    }
    const float inv = 1.0f / (float)W_;
    s1 *= inv; s2 *= inv;
    f32x4* xr = (f32x4*)(x + (size_t)m * E_);
    xr[lane] = s1;
    if (lane < 11) xr[64 + lane] = s2;
  } else {
    int idx = (blk - 4096) * 256 + threadIdx.x;
    if (idx < E_ * 768) {
      int k = idx / 768, g = idx % 768;
      Wt_ih[idx] = (g < 384) ? Wih_f[g * E_ + k] : Wih_b[(g - 384) * E_ + k];
    }
    if (idx < 768) bias_ih[idx] = (idx < 384) ? bih_f[idx] : bih_b[idx - 384];
    if (idx < 512 * 128) { int k = idx / 128, j = idx % 128; W1t[idx] = W1[j * 512 + k]; }
  }
}

// ---------------- gemm64: 64x64 tile (small-M) ----------------
template<bool BIAS, bool ACCUM, bool RELU>
__global__ __launch_bounds__(256) void gemm64(
    const float* __restrict__ A, int lda,
    const float* __restrict__ B, int ldb,
    float* __restrict__ C, int ldc,
    const float* __restrict__ bias,
    int M, int N, int K) {
  __shared__ float As[16][68];
  __shared__ float Bs[16][68];
  const int tid = threadIdx.x;
  const int n0 = blockIdx.x * 64, m0 = blockIdx.y * 64;
  const int tx = tid & 15, ty = tid >> 4;
  const int am = tid >> 2, ak = (tid & 3) << 2;
  const int bk = tid >> 4, bn = (tid & 15) << 2;
  float acc[4][4] = {};
  for (int k0 = 0; k0 < K; k0 += 16) {
    float4 av = make_float4(0.f, 0.f, 0.f, 0.f);
    int arow = m0 + am;
    if (arow < M) {
      if (k0 + ak + 3 < K) {
        av = *(const float4*)(A + (size_t)arow * lda + k0 + ak);
      } else {
        float tmp[4] = {0.f, 0.f, 0.f, 0.f};
        #pragma unroll
        for (int i2 = 0; i2 < 4; i2++) { int k = k0 + ak + i2; if (k < K) tmp[i2] = A[(size_t)arow * lda + k]; }
        av = make_float4(tmp[0], tmp[1], tmp[2], tmp[3]);
      }
    }
    As[ak + 0][am] = av.x; As[ak + 1][am] = av.y; As[ak + 2][am] = av.z; As[ak + 3][am] = av.w;
    float4 bv = make_float4(0.f, 0.f, 0.f, 0.f);
    {
      int k = k0 + bk;
      if (k < K) bv = *(const float4*)(B + (size_t)k * ldb + n0 + bn);
    }
    *(float4*)&Bs[bk][bn] = bv;
    __syncthreads();
    #pragma unroll
    for (int kk = 0; kk < 16; kk++) {
      float4 a = *(const float4*)&As[kk][ty << 2];
      float4 b = *(const float4*)&Bs[kk][tx << 2];
      acc[0][0] = fmaf(a.x, b.x, acc[0][0]); acc[0][1] = fmaf(a.x, b.y, acc[0][1]);
      acc[0][2] = fmaf(a.x, b.z, acc[0][2]); acc[0][3] = fmaf(a.x, b.w, acc[0][3]);
      acc[1][0] = fmaf(a.y, b.x, acc[1][0]); acc[1][1] = fmaf(a.y, b.y, acc[1][1]);
      acc[1][2] = fmaf(a.y, b.z, acc[1][2]); acc[1][3] = fmaf(a.y, b.w, acc[1][3]);
      acc[2][0] = fmaf(a.z, b.x, acc[2][0]); acc[2][1] = fmaf(a.z, b.y, acc[2][1]);
      acc[2][2] = fmaf(a.z, b.z, acc[2][2]); acc[2][3] = fmaf(a.z, b.w, acc[2][3]);
      acc[3][0] = fmaf(a.w, b.x, acc[3][0]); acc[3][1] = fmaf(a.w, b.y, acc[3][1]);
      acc[3][2] = fmaf(a.w, b.z, acc[3][2]); acc[3][3] = fmaf(a.w, b.w, acc[3][3]);
    }
    __syncthreads();
  }
  float4 bias4 = make_float4(0.f, 0.f, 0.f, 0.f);
  if (BIAS) bias4 = *(const float4*)(bias + n0 + (tx << 2));
  #pragma unroll
  for (int i = 0; i < 4; i++) {
    int row = m0 + (ty << 2) + i;
    if (row >= M) break;
    float* cp = C + (size_t)row * ldc + n0 + (tx << 2);
    float4 v = make_float4(acc[i][0], acc[i][1], acc[i][2], acc[i][3]);
    if (BIAS) { v.x += bias4.x; v.y += bias4.y; v.z += bias4.z; v.w += bias4.w; }
    if (ACCUM) { float4 o = *(const float4*)cp; v.x += o.x; v.y += o.y; v.z += o.z; v.w += o.w; }
    if (RELU) { v.x = fmaxf(v.x, 0.f); v.y = fmaxf(v.y, 0.f); v.z = fmaxf(v.z, 0.f); v.w = fmaxf(v.w, 0.f); }
    *(float4*)cp = v;
  }
}

// ---------------- gemm128x64: 128x64 tile, 8x4 acc ----------------
template<bool BIAS>
__global__ __launch_bounds__(256) void gemm128x64(
    const float* __restrict__ A, int lda,
    const float* __restrict__ B, int ldb,
    float* __restrict__ C, int ldc,
    const float* __restrict__ bias,
    int M, int N, int K) {
  __shared__ float As[16][132];
  __shared__ float Bs[16][68];
  const int tid = threadIdx.x;
  const int n0 = blockIdx.x * 64, m0 = blockIdx.y * 128;
  const int tx = tid & 15, ty = tid >> 4;
  const int am = tid >> 1, ak = (tid & 1) << 3;   // A: row am, 8 k's
  const int bk = tid >> 4, bn = (tid & 15) << 2;  // B: row bk, 4 n's
  float acc[8][4] = {};
  for (int k0 = 0; k0 < K; k0 += 16) {
    {
      const float* ap = A + (size_t)(m0 + am) * lda + k0 + ak;
      float a0[8];
      if (k0 + ak + 7 < K) {
        float4 v0 = *(const float4*)ap, v1 = *(const float4*)(ap + 4);
        a0[0] = v0.x; a0[1] = v0.y; a0[2] = v0.z; a0[3] = v0.w;
        a0[4] = v1.x; a0[5] = v1.y; a0[6] = v1.z; a0[7] = v1.w;
      } else {
        #pragma unroll
        for (int i = 0; i < 8; i++) { int k = k0 + ak + i; a0[i] = (k < K) ? ap[i] : 0.f; }
      }
      #pragma unroll
      for (int i = 0; i < 8; i++) As[ak + i][am] = a0[i];
    }
    {
      float4 bv = make_float4(0.f, 0.f, 0.f, 0.f);
      int k = k0 + bk;
      if (k < K) bv = *(const float4*)(B + (size_t)k * ldb + n0 + bn);
      *(float4*)&Bs[bk][bn] = bv;
    }
    __syncthreads();
    #pragma unroll
    for (int kk = 0; kk < 16; kk++) {
      float4 a0 = *(const float4*)&As[kk][ty << 3];
      float4 a1 = *(const float4*)&As[kk][(ty << 3) + 4];
      float4 b = *(const float4*)&Bs[kk][tx << 2];
      float av[8] = {a0.x, a0.y, a0.z, a0.w, a1.x, a1.y, a1.z, a1.w};
      #pragma unroll
      for (int i = 0; i < 8; i++) {
        acc[i][0] = fmaf(av[i], b.x, acc[i][0]);
        acc[i][1] = fmaf(av[i], b.y, acc[i][1]);
        acc[i][2] = fmaf(av[i], b.z, acc[i][2]);
        acc[i][3] = fmaf(av[i], b.w, acc[i][3]);
      }
    }
    __syncthreads();
  }
  float4 bias4 = make_float4(0.f, 0.f, 0.f, 0.f);
  if (BIAS) bias4 = *(const float4*)(bias + n0 + (tx << 2));
  #pragma unroll
  for (int i = 0; i < 8; i++) {
    float* cp = C + (size_t)(m0 + (ty << 3) + i) * ldc + n0 + (tx << 2);
    float4 v = make_float4(acc[i][0], acc[i][1], acc[i][2], acc[i][3]);
    if (BIAS) { v.x += bias4.x; v.y += bias4.y; v.z += bias4.z; v.w += bias4.w; }
    *(float4*)cp = v;
  }
}

// ---------------- dual_logits: out = relu(A1@B[0:256] + A2@B[256:512] + b1) . W2 + b2 ----------------
// Each block computes 64 rows x ALL 128 cols (acc 4x8/thread, 32 VGPR), so the
// h row never touches HBM: bias+relu in regs, dot with W2, 16-lane butterfly.
// Eliminates the [M,128] h buffer (8MB write + 8MB read) and the logits launch.
__global__ __launch_bounds__(256) void dual_logits_kernel(
    const float* __restrict__ A1, const float* __restrict__ A2, int lda,  // [M,256] each
    const float* __restrict__ B, int ldb,    // [512,128] = W1t
    const float* __restrict__ bias,          // b1 [128]
    const float* __restrict__ W2, const float* __restrict__ b2,
    float* __restrict__ out, int M) {
  const int K = 512, KH = 256;
  __shared__ float As[16][68];
  __shared__ float Bs[16][132];
  const int tid = threadIdx.x;
  const int m0 = blockIdx.x * 64;
  const int tx = tid & 15, ty = tid >> 4;
  const int am = tid >> 2, ak = (tid & 3) << 2;   // A: 64 rows x 16 k
  const int bk = tid >> 4, bn = (tid & 15) << 3;  // B: 16 k x 128 cols (8/thread)
  float acc[4][8] = {};
  for (int k0 = 0; k0 < K; k0 += 16) {
    int k = k0 + ak;
    const float* Arow = (k < KH) ? (A1 + (size_t)(m0 + am) * lda + k)
                                 : (A2 + (size_t)(m0 + am) * lda + (k - KH));
    float4 av = *(const float4*)Arow;
    As[ak + 0][am] = av.x; As[ak + 1][am] = av.y; As[ak + 2][am] = av.z; As[ak + 3][am] = av.w;
    const float* bp = B + (size_t)(k0 + bk) * ldb + bn;
    float4 b0 = *(const float4*)bp, b1v = *(const float4*)(bp + 4);
    *(float4*)&Bs[bk][bn] = b0;
    *(float4*)&Bs[bk][bn + 4] = b1v;
    __syncthreads();
    #pragma unroll
    for (int kk = 0; kk < 16; kk++) {
      float4 a = *(const float4*)&As[kk][ty << 2];
      float4 b0_ = *(const float4*)&Bs[kk][tx << 3];
      float4 b1_ = *(const float4*)&Bs[kk][(tx << 3) + 4];
      float av_[4] = {a.x, a.y, a.z, a.w};
      float bv_[8] = {b0_.x, b0_.y, b0_.z, b0_.w, b1_.x, b1_.y, b1_.z, b1_.w};
      #pragma unroll
      for (int i = 0; i < 4; i++)
        #pragma unroll
        for (int j = 0; j < 8; j++)
          acc[i][j] = fmaf(av_[i], bv_[j], acc[i][j]);
    }
    __syncthreads();
  }
  // epilogue: h = relu(acc + b1); logits partial over this thread's 8 cols
  float biasv[8], w2v[8];
  #pragma unroll
  for (int j = 0; j < 8; j++) {
    biasv[j] = bias[(tx << 3) + j];
    w2v[j] = W2[(tx << 3) + j];
  }
  const float b2v = b2[0];
  #pragma unroll
  for (int i = 0; i < 4; i++) {
    float part = 0.f;
    #pragma unroll
    for (int j = 0; j < 8; j++) {
      float h = fmaxf(acc[i][j] + biasv[j], 0.f);
      part = fmaf(h, w2v[j], part);
    }
    part += __shfl_xor(part, 1); part += __shfl_xor(part, 2);
    part += __shfl_xor(part, 4); part += __shfl_xor(part, 8);
    if (tx == 0) out[m0 + (ty << 2) + i] = part + b2v;
  }
}

// ---------------- GRU recurrence v13-final (round-13 best: 373.8 us) ----------------
// 64 blocks = (dir,doc), 512 threads: thread = (row j = t>>2, quarter q = t&3),
// 96 weights parked in a0..a95 (outside RA's domain -> unspillable),
// accvgpr_read bounce, DPP quad butterfly, swizzled dbuf h, lgkm-only barrier.
// Structural floor ~1750 cyc/step: exposed serial chain with 2 waves/SIMD
// (register-file-capped: 80 VGPR + 96 AGPR). v10/v14 (4 waves, 8-way split)
// both regressed ~35% from redundant per-lane activation overhead.
#define SWZ(k) ((k) + 4 * ((k) >> 4))
#define BAR_LGKM() asm volatile("s_waitcnt lgkmcnt(0)\n\ts_barrier" ::: "memory")

#define QADD(X, CTRL) do { \
    int _t = __builtin_amdgcn_update_dpp(0, __float_as_int(X), CTRL, 0xF, 0xF, true); \
    X += __int_as_float(_t); } while (0)
// quad_perm [1,0,3,2] = 0xB1 (xor1) ; [2,3,0,1] = 0x4E (xor2)

#define AW(N, V) asm volatile("v_accvgpr_write_b32 a" #N ", %0" :: "v"(V) : "a" #N)
#define AWQ(N0, N1, N2, N3, Q) do { AW(N0, (Q).x); AW(N1, (Q).y); AW(N2, (Q).z); AW(N3, (Q).w); } while (0)

#define A96CLOB \
  "a0","a1","a2","a3","a4","a5","a6","a7","a8","a9","a10","a11","a12","a13","a14","a15", \
  "a16","a17","a18","a19","a20","a21","a22","a23","a24","a25","a26","a27","a28","a29","a30","a31", \
  "a32","a33","a34","a35","a36","a37","a38","a39","a40","a41","a42","a43","a44","a45","a46","a47", \
  "a48","a49","a50","a51","a52","a53","a54","a55","a56","a57","a58","a59","a60","a61","a62","a63", \
  "a64","a65","a66","a67","a68","a69","a70","a71","a72","a73","a74","a75","a76","a77","a78","a79", \
  "a80","a81","a82","a83","a84","a85","a86","a87","a88","a89","a90","a91","a92","a93","a94","a95"

#define RD(T, N) "v_accvgpr_read_b32 %[" #T "], a" #N "\n\t"
#define FM(P, T, X) "v_fmac_f32 %[" #P "], %[" #T "], %[" #X "]\n\t"
#define COLA(CR, CZ, CN, X) \
  RD(t0, CR) RD(t1, CZ) RD(t2, CN) FM(pr, t0, X) FM(pz, t1, X) FM(pn, t2, X)

__global__ __launch_bounds__(512, 2) void gru_kernel(
    const float* __restrict__ gxbuf,   // [M,768] : row b*512+s, cols [dir*384 + gate*128 + j]
    const float* __restrict__ Whh_f, const float* __restrict__ Whh_b,
    const float* __restrict__ bhh_f, const float* __restrict__ bhh_b,
    float* __restrict__ sent_rep,      // [B,S,256]
    float* __restrict__ last_f, float* __restrict__ last_b) {
  const int bid = blockIdx.x;          // 64 = dir*32 + b
  const int dir = bid >> 5, b = bid & 31;
  const int t = threadIdx.x;           // 0..511
  const int j = t >> 2;                // row 0..127
  const int q = t & 3;                 // k-quarter 0..3 (32 cols each)
  const int k0 = q << 5;
  const float* Whh = dir ? Whh_b : Whh_f;
  const float* bhh = dir ? bhh_b : bhh_f;

  // ---- load 96 weight floats and park them in a0..a95 ----
  {
    const float* Wr = Whh + (size_t)j * 128 + k0;
    const float* Wz = Whh + (size_t)(128 + j) * 128 + k0;
    const float* Wn = Whh + (size_t)(256 + j) * 128 + k0;
    f32x4 w0 = *(const f32x4*)(Wr + 0),  w1 = *(const f32x4*)(Wr + 4);
    f32x4 w2 = *(const f32x4*)(Wr + 8),  w3 = *(const f32x4*)(Wr + 12);
    f32x4 w4 = *(const f32x4*)(Wr + 16), w5 = *(const f32x4*)(Wr + 20);
    f32x4 w6 = *(const f32x4*)(Wr + 24), w7 = *(const f32x4*)(Wr + 28);
    AWQ(0, 1, 2, 3, w0);   AWQ(4, 5, 6, 7, w1);   AWQ(8, 9, 10, 11, w2);  AWQ(12, 13, 14, 15, w3);
    AWQ(16, 17, 18, 19, w4); AWQ(20, 21, 22, 23, w5); AWQ(24, 25, 26, 27, w6); AWQ(28, 29, 30, 31, w7);
    w0 = *(const f32x4*)(Wz + 0);  w1 = *(const f32x4*)(Wz + 4);
    w2 = *(const f32x4*)(Wz + 8);  w3 = *(const f32x4*)(Wz + 12);
    w4 = *(const f32x4*)(Wz + 16); w5 = *(const f32x4*)(Wz + 20);
    w6 = *(const f32x4*)(Wz + 24); w7 = *(const f32x4*)(Wz + 28);
    AWQ(32, 33, 34, 35, w0); AWQ(36, 37, 38, 39, w1); AWQ(40, 41, 42, 43, w2); AWQ(44, 45, 46, 47, w3);
    AWQ(48, 49, 50, 51, w4); AWQ(52, 53, 54, 55, w5); AWQ(56, 57, 58, 59, w6); AWQ(60, 61, 62, 63, w7);
    w0 = *(const f32x4*)(Wn + 0);  w1 = *(const f32x4*)(Wn + 4);
    w2 = *(const f32x4*)(Wn + 8);  w3 = *(const f32x4*)(Wn + 12);
    w4 = *(const f32x4*)(Wn + 16); w5 = *(const f32x4*)(Wn + 20);
    w6 = *(const f32x4*)(Wn + 24); w7 = *(const f32x4*)(Wn + 28);
    AWQ(64, 65, 66, 67, w0); AWQ(68, 69, 70, 71, w1); AWQ(72, 73, 74, 75, w2); AWQ(76, 77, 78, 79, w3);
    AWQ(80, 81, 82, 83, w4); AWQ(84, 85, 86, 87, w5); AWQ(88, 89, 90, 91, w6); AWQ(92, 93, 94, 95, w7);
  }

  // per-lane bias folds (q==0 lane carries all three; summed by the butterfly)
  const float cR = (q == 0) ? bhh[j] : 0.f;
  const float cZ = (q == 0) ? bhh[128 + j] : 0.f;
  const float cN = (q == 0) ? bhh[256 + j] : 0.f;
  // gx gate for this lane: q1->r, q2->z, q0/q3->n (q0 uses gx_c as gn directly)
  const int gate = (q == 1) ? 0 : (q == 2) ? 1 : 2;
  const float mr = (q == 1) ? 1.f : 0.f;
  const float mz = (q == 2) ? 1.f : 0.f;

  __shared__ float lds[320];           // 2 x 160-word swizzled h buffers
  if (t < 128) lds[SWZ(t)] = 0.f;
  __syncthreads();

  const int stp = dir ? -1 : 1;
  const int ts0 = dir ? 511 : 0;
  const ptrdiff_t g768 = (ptrdiff_t)stp * 768;
  const ptrdiff_t s256 = (ptrdiff_t)stp * 256;
  const float* gq = gxbuf + (size_t)b * 512 * 768 + dir * 384 + gate * 128 + j + (size_t)ts0 * 768;
  float* sp = sent_rep + (size_t)b * 512 * 256 + dir * 128 + (size_t)ts0 * 256;
  float hprev = 0.f;
  float gx_c = gq[0];
  float gx_1 = gq[g768];

#define GRU_STEP(P, SOFF) do { \
    float gx_2 = 0.f; \
    if (s + 2 + (SOFF) < 512) gx_2 = gq[2 * g768]; \
    const f32x4* hv = (const f32x4*)(lds + (P) * 160 + 40 * q); \
    f32x4 h0 = hv[0], h1 = hv[1], h2 = hv[2], h3 = hv[3]; \
    f32x4 h4 = hv[5], h5 = hv[6], h6 = hv[7], h7 = hv[8]; \
    float pr = cR, pz = cZ, pn = cN; \
    { float t0v, t1v, t2v; \
      asm volatile( \
        COLA(0,32,64,x0)   COLA(1,33,65,x1)   COLA(2,34,66,x2)   COLA(3,35,67,x3) \
        COLA(4,36,68,x4)   COLA(5,37,69,x5)   COLA(6,38,70,x6)   COLA(7,39,71,x7) \
        COLA(8,40,72,x8)   COLA(9,41,73,x9)   COLA(10,42,74,x10) COLA(11,43,75,x11) \
        COLA(12,44,76,x12) COLA(13,45,77,x13) COLA(14,46,78,x14) COLA(15,47,79,x15) \
        : [pr]"+v"(pr), [pz]"+v"(pz), [pn]"+v"(pn), \
          [t0]"=&v"(t0v), [t1]"=&v"(t1v), [t2]"=&v"(t2v) \
        : [x0]"v"(h0.x), [x1]"v"(h0.y), [x2]"v"(h0.z), [x3]"v"(h0.w), \
          [x4]"v"(h1.x), [x5]"v"(h1.y), [x6]"v"(h1.z), [x7]"v"(h1.w), \
          [x8]"v"(h2.x), [x9]"v"(h2.y), [x10]"v"(h2.z), [x11]"v"(h2.w), \
          [x12]"v"(h3.x), [x13]"v"(h3.y), [x14]"v"(h3.z), [x15]"v"(h3.w) \
        : A96CLOB); \
      asm volatile( \
        COLA(16,48,80,x0)  COLA(17,49,81,x1)  COLA(18,50,82,x2)  COLA(19,51,83,x3) \
        COLA(20,52,84,x4)  COLA(21,53,85,x5)  COLA(22,54,86,x6)  COLA(23,55,87,x7) \
        COLA(24,56,88,x8)  COLA(25,57,89,x9)  COLA(26,58,90,x10) COLA(27,59,91,x11) \
        COLA(28,60,92,x12) COLA(29,61,93,x13) COLA(30,62,94,x14) COLA(31,63,95,x15) \
        : [pr]"+v"(pr), [pz]"+v"(pz), [pn]"+v"(pn), \
          [t0]"=&v"(t0v), [t1]"=&v"(t1v), [t2]"=&v"(t2v) \
        : [x0]"v"(h4.x), [x1]"v"(h4.y), [x2]"v"(h4.z), [x3]"v"(h4.w), \
          [x4]"v"(h5.x), [x5]"v"(h5.y), [x6]"v"(h5.z), [x7]"v"(h5.w), \
          [x8]"v"(h6.x), [x9]"v"(h6.y), [x10]"v"(h6.z), [x11]"v"(h6.w), \
          [x12]"v"(h7.x), [x13]"v"(h7.y), [x14]"v"(h7.z), [x15]"v"(h7.w) \
        : A96CLOB); } \
    pr = fmaf(mr, gx_c, pr); \
    pz = fmaf(mz, gx_c, pz); \
    QADD(pr, 0xB1); QADD(pr, 0x4E); \
    QADD(pz, 0xB1); QADD(pz, 0x4E); \
    QADD(pn, 0xB1); QADD(pn, 0x4E); \
    float xr = fminf(fmaxf(pr, -30.f), 30.f); \
    float xz = fminf(fmaxf(pz, -30.f), 30.f); \
    float r = 1.f / (1.f + __expf(-xr)); \
    float z = 1.f / (1.f + __expf(-xz)); \
    float xn = gx_c + r * pn; xn = fminf(fmaxf(xn, -15.f), 15.f); \
    float e2 = __expf(2.f * xn); \
    float n = (e2 - 1.f) / (e2 + 1.f); \
    float hnew = (1.f - z) * n + z * hprev; \
    hprev = hnew; \
    if (q == 0) { \
      lds[((P) ^ 1) * 160 + SWZ(j)] = hnew; \
      sp[j] = hnew; \
    } \
    BAR_LGKM(); \
    gq += g768; sp += s256; \
    gx_c = gx_1; gx_1 = gx_2; \
  } while (0)

  #pragma unroll 1
  for (int s = 0; s < 512; s += 2) {
    GRU_STEP(0, 0);
    GRU_STEP(1, 1);
  }
#undef GRU_STEP

  if (q == 0) (dir ? last_b : last_f)[b * 128 + j] = hprev;
}

// ---------------- fused misc: topicmat (blocks 0..511) + docvec (512..543) + seg (544..607) ----------------
__global__ void misc_kernel(const float* __restrict__ sent_rep, const int* __restrict__ tse,
                            const float* __restrict__ last_f, const float* __restrict__ last_b,
                            float* __restrict__ topic_mat, float* __restrict__ doc_vec,
                            int* __restrict__ seg) {
  int blk = blockIdx.x;
  if (blk < 512) {
    int b = blk >> 4, t = blk & 15;
    int st = tse[(b * 16 + t) * 2 + 0];   // 1-based
    int en = tse[(b * 16 + t) * 2 + 1];
    int jj = threadIdx.x;                 // 0..255
    const float* sr = sent_rep + (size_t)b * 512 * 256;
    float val;
    if (jj < 128) {
      float a = sr[(size_t)(en - 1) * 256 + jj];
      float c = (st - 2 >= 0) ? sr[(size_t)(st - 2) * 256 + jj] : 0.f;
      val = a - c;
    } else {
      float a = sr[(size_t)(st - 1) * 256 + jj];
      float c = (en <= 511) ? sr[(size_t)en * 256 + jj] : 0.f;
      val = a - c;
    }
    topic_mat[(size_t)blk * 256 + jj] = val;
  } else if (blk < 544) {
    int idx = (blk - 512) * 256 + threadIdx.x;  // 8192
    int i = idx >> 8, c = idx & 255;
    const float* src = (i < 16) ? last_f : last_b;
    int ii = (i < 16) ? i : i - 16;
    int bb = 2 * ii + (c >> 7);
    doc_vec[idx] = src[bb * 128 + (c & 127)];
  } else {
    int idx = (blk - 544) * 256 + threadIdx.x;  // 16384
    int b = idx >> 9, s = idx & 511;
    int pos = s + 1, cnt = 0;
    for (int t = 0; t < T_; t++) cnt += (tse[(b * T_ + t) * 2] <= pos);
    int sg = cnt - 1; sg = sg < 0 ? 0 : (sg > T_ - 1 ? T_ - 1 : sg);
    seg[idx] = sg;
  }
}

// ---------------- scores + ratios + context (wave per row) ----------------
__global__ void scores_ctx_kernel(const float* __restrict__ sr_part,     // [M,512]
                                  const float* __restrict__ doc_part,    // [32,512]
                                  const float* __restrict__ topic_part,  // [32,16,512]
                                  const float* __restrict__ v_att,       // [512]
                                  const float* __restrict__ doc_vec,     // [32,256]
                                  const float* __restrict__ topic_mat,   // [32,16,256]
                                  const int* __restrict__ seg,           // [M]
                                  float* __restrict__ context) {         // [M,256]
  int wid = threadIdx.x >> 6, lane = threadIdx.x & 63;
  int row = blockIdx.x * 4 + wid;
  int b = row >> 9;
  int sg = seg[row];
  const float* srp = sr_part + (size_t)row * 512;
  const float* dp = doc_part + (size_t)b * 512;
  const float* tp = topic_part + (size_t)(b * 16 + sg) * 512;
  float accd = 0.f, acct = 0.f;
  #pragma unroll
  for (int i = 0; i < 8; i++) {
    int n = lane + i * 64;
    float sp = srp[n], va = v_att[n];
    accd += tanhf(dp[n] + sp) * va;
    acct += tanhf(tp[n] + sp) * va;
  }
  #pragma unroll
  for (int off = 32; off; off >>= 1) { accd += __shfl_xor(accd, off); acct += __shfl_xor(acct, off); }
  float ssum = accd + acct;
  float rd = accd / ssum, rt = acct / ssum;
  const float* dv = doc_vec + (size_t)b * 256;
  const float* tm = topic_mat + (size_t)(b * 16 + sg) * 256;
  float* ctx = context + (size_t)row * 256;
  #pragma unroll
  for (int i = 0; i < 4; i++) {
    int jj = lane + i * 64;
    ctx[jj] = rd * dv[jj] + rt * tm[jj];
  }
}

extern "C" void kernel_launch(void* const* d_in, const int* in_sizes, int n_in,
                              void* d_out, int out_size, void* d_ws, size_t ws_size,
                              hipStream_t stream) {
  const int*   word_ids = (const int*)d_in[0];
  const int*   tse      = (const int*)d_in[1];
  const float* emb      = (const float*)d_in[2];
  const float* Wih_f    = (const float*)d_in[3];
  const float* Whh_f    = (const float*)d_in[4];
  const float* bih_f    = (const float*)d_in[5];
  const float* bhh_f    = (const float*)d_in[6];
  const float* Wih_b    = (const float*)d_in[7];
  const float* Whh_b    = (const float*)d_in[8];
  const float* bih_b    = (const float*)d_in[9];
  const float* bhh_b    = (const float*)d_in[10];
  const float* W_att    = (const float*)d_in[11];
  const float* v_att    = (const float*)d_in[12];
  const float* W1       = (const float*)d_in[13];
  const float* b1       = (const float*)d_in[14];
  const float* W2       = (const float*)d_in[15];
  const float* b2       = (const float*)d_in[16];
  float* ws  = (float*)d_ws;
  float* out = (float*)d_out;

  // fused embed_mean + prep (900 prep blocks appended)
  embed_prep_kernel<<<M_ / 4 + 900, 256, 0, stream>>>(
      word_ids, emb, ws + OFF_X,
      Wih_f, Wih_b, bih_f, bih_b, W1,
      ws + OFF_WTIH, ws + OFF_BIASIH, ws + OFF_W1T);
  // gx = x @ [Wih_f|Wih_b]^T + bias  -> [M,768]
  gemm128x64<true><<<dim3(12, 128), 256, 0, stream>>>(
      ws + OFF_X, E_, ws + OFF_WTIH, 768, ws + OFF_GX, 768, ws + OFF_BIASIH, M_, 768, E_);
  gru_kernel<<<64, 512, 0, stream>>>(ws + OFF_GX, Whh_f, Whh_b, bhh_f, bhh_b,
                                     ws + OFF_SENT, ws + OFF_LASTF, ws + OFF_LASTB);
  // fused: topicmat + docvec + seg
  misc_kernel<<<608, 256, 0, stream>>>(ws + OFF_SENT, tse, ws + OFF_LASTF, ws + OFF_LASTB,
                                       ws + OFF_TOPICMAT, ws + OFF_DOCVEC, (int*)(ws + OFF_SEG));
  // doc_part = doc_vec @ W_att[0:256,:]
  gemm64<false, false, false><<<dim3(8, 1), 256, 0, stream>>>(
      ws + OFF_DOCVEC, 256, W_att, 512, ws + OFF_DOCPART, 512, nullptr, 32, 512, 256);
  // topic_part = topic_mat @ W_att[0:256,:]   (M=512 -> 4 row-blocks)
  gemm128x64<false><<<dim3(8, 4), 256, 0, stream>>>(
      ws + OFF_TOPICMAT, 256, W_att, 512, ws + OFF_TOPICPART, 512, nullptr, 512, 512, 256);
  // sr_part = sent_rep @ W_att[256:512,:]
  gemm128x64<false><<<dim3(8, 128), 256, 0, stream>>>(
      ws + OFF_SENT, 256, W_att + 256 * 512, 512, ws + OFF_SRPART, 512, nullptr, M_, 512, 256);
  scores_ctx_kernel<<<M_ / 4, 256, 0, stream>>>(
      ws + OFF_SRPART, ws + OFF_DOCPART, ws + OFF_TOPICPART, v_att,
      ws + OFF_DOCVEC, ws + OFF_TOPICMAT, (const int*)(ws + OFF_SEG), ws + OFF_CTX);
  // logits = relu(sent_rep@W1t[0:256] + ctx@W1t[256:512] + b1) . W2 + b2  (fully fused)
  dual_logits_kernel<<<M_ / 64, 256, 0, stream>>>(
      ws + OFF_SENT, ws + OFF_CTX, 256, ws + OFF_W1T, 128, b1, W2, b2, out, M_);
}

// Round 19
// 691.660 us; speedup vs baseline: 1.0095x; 1.0095x over previous
//
#include <hip/hip_runtime.h>
#include <hip/hip_bf16.h>

#define B_ 32
#define S_ 512
#define W_ 20
#define T_ 16
#define E_ 300
#define H_ 128
#define M_ (B_*S_)   // 16384

typedef float f32x4 __attribute__((ext_vector_type(4)));

// workspace offsets (floats)
#define OFF_GX        0ul          // [M,768]   (dead after GRU -> reused by SRPART)
#define OFF_X         12582912ul   // [M,300]   (dead after gx GEMM -> reused by CTX)
#define OFF_SENT      17498112ul   // [M,256]
#define OFF_LASTF     21692416ul   // [32,128]
#define OFF_LASTB     21696512ul   // [32,128]
#define OFF_DOCVEC    21700608ul   // [32,256]
#define OFF_TOPICMAT  21708800ul   // [32,16,256]
#define OFF_DOCPART   21839872ul   // [32,512]
#define OFF_TOPICPART 21856256ul   // [32,16,512]
#define OFF_SEG       22118400ul   // [M] int
#define OFF_WTIH      22134784ul   // [300,768]
#define OFF_BIASIH    22365184ul   // [768]
#define OFF_W1T       22365952ul   // [512,128]
#define OFF_H         22431488ul   // [M,128]
#define OFF_SRPART    0ul          // overlay GX: [M,512]
#define OFF_CTX       OFF_X        // overlay X:  [M,256]

// ---------------- prep: transposes + bias concat ----------------
__global__ void prep_kernel(const float* __restrict__ Wih_f, const float* __restrict__ Wih_b,
                            const float* __restrict__ bih_f, const float* __restrict__ bih_b,
                            const float* __restrict__ W1,
                            float* __restrict__ Wt_ih, float* __restrict__ bias_ih,
                            float* __restrict__ W1t) {
  int idx = blockIdx.x * 256 + threadIdx.x;
  if (idx < E_ * 768) {
    int k = idx / 768, g = idx % 768;
    Wt_ih[idx] = (g < 384) ? Wih_f[g * E_ + k] : Wih_b[(g - 384) * E_ + k];
  }
  if (idx < 768) bias_ih[idx] = (idx < 384) ? bih_f[idx] : bih_b[idx - 384];
  if (idx < 512 * 128) { int k = idx / 128, j = idx % 128; W1t[idx] = W1[j * 512 + k]; }
}

// ---------------- embedding mean v2: wave per sentence, float4 loads ----------------
__global__ __launch_bounds__(256) void embed_mean_kernel(
    const int* __restrict__ wid, const float* __restrict__ emb, float* __restrict__ x) {
  int m = blockIdx.x * 4 + (threadIdx.x >> 6);   // sentence (4 per block)
  int lane = threadIdx.x & 63;
  const int* ids = wid + (size_t)m * W_;
  f32x4 s1 = {0.f, 0.f, 0.f, 0.f}, s2 = {0.f, 0.f, 0.f, 0.f};
  for (int w = 0; w < W_; w++) {
    const f32x4* row = (const f32x4*)(emb + (size_t)ids[w] * E_);  // 75 float4
    s1 += row[lane];
    if (lane < 11) s2 += row[64 + lane];
  }
  const float inv = 1.0f / (float)W_;
  s1 *= inv; s2 *= inv;
  f32x4* xr = (f32x4*)(x + (size_t)m * E_);
  xr[lane] = s1;
  if (lane < 11) xr[64 + lane] = s2;
}

// ---------------- gemm64: 64x64 tile (small-M / dual) ----------------
template<bool BIAS, bool ACCUM, bool RELU>
__global__ __launch_bounds__(256) void gemm64(
    const float* __restrict__ A, int lda,
    const float* __restrict__ B, int ldb,
    float* __restrict__ C, int ldc,
    const float* __restrict__ bias,
    int M, int N, int K) {
  __shared__ float As[16][68];
  __shared__ float Bs[16][68];
  const int tid = threadIdx.x;
  const int n0 = blockIdx.x * 64, m0 = blockIdx.y * 64;
  const int tx = tid & 15, ty = tid >> 4;
  const int am = tid >> 2, ak = (tid & 3) << 2;
  const int bk = tid >> 4, bn = (tid & 15) << 2;
  float acc[4][4] = {};
  for (int k0 = 0; k0 < K; k0 += 16) {
    float4 av = make_float4(0.f, 0.f, 0.f, 0.f);
    int arow = m0 + am;
    if (arow < M) {
      if (k0 + ak + 3 < K) {
        av = *(const float4*)(A + (size_t)arow * lda + k0 + ak);
      } else {
        float tmp[4] = {0.f, 0.f, 0.f, 0.f};
        #pragma unroll
        for (int i2 = 0; i2 < 4; i2++) { int k = k0 + ak + i2; if (k < K) tmp[i2] = A[(size_t)arow * lda + k]; }
        av = make_float4(tmp[0], tmp[1], tmp[2], tmp[3]);
      }
    }
    As[ak + 0][am] = av.x; As[ak + 1][am] = av.y; As[ak + 2][am] = av.z; As[ak + 3][am] = av.w;
    float4 bv = make_float4(0.f, 0.f, 0.f, 0.f);
    {
      int k = k0 + bk;
      if (k < K) bv = *(const float4*)(B + (size_t)k * ldb + n0 + bn);
    }
    *(float4*)&Bs[bk][bn] = bv;
    __syncthreads();
    #pragma unroll
    for (int kk = 0; kk < 16; kk++) {
      float4 a = *(const float4*)&As[kk][ty << 2];
      float4 b = *(const float4*)&Bs[kk][tx << 2];
      acc[0][0] = fmaf(a.x, b.x, acc[0][0]); acc[0][1] = fmaf(a.x, b.y, acc[0][1]);
      acc[0][2] = fmaf(a.x, b.z, acc[0][2]); acc[0][3] = fmaf(a.x, b.w, acc[0][3]);
      acc[1][0] = fmaf(a.y, b.x, acc[1][0]); acc[1][1] = fmaf(a.y, b.y, acc[1][1]);
      acc[1][2] = fmaf(a.y, b.z, acc[1][2]); acc[1][3] = fmaf(a.y, b.w, acc[1][3]);
      acc[2][0] = fmaf(a.z, b.x, acc[2][0]); acc[2][1] = fmaf(a.z, b.y, acc[2][1]);
      acc[2][2] = fmaf(a.z, b.z, acc[2][2]); acc[2][3] = fmaf(a.z, b.w, acc[2][3]);
      acc[3][0] = fmaf(a.w, b.x, acc[3][0]); acc[3][1] = fmaf(a.w, b.y, acc[3][1]);
      acc[3][2] = fmaf(a.w, b.z, acc[3][2]); acc[3][3] = fmaf(a.w, b.w, acc[3][3]);
    }
    __syncthreads();
  }
  float4 bias4 = make_float4(0.f, 0.f, 0.f, 0.f);
  if (BIAS) bias4 = *(const float4*)(bias + n0 + (tx << 2));
  #pragma unroll
  for (int i = 0; i < 4; i++) {
    int row = m0 + (ty << 2) + i;
    if (row >= M) break;
    float* cp = C + (size_t)row * ldc + n0 + (tx << 2);
    float4 v = make_float4(acc[i][0], acc[i][1], acc[i][2], acc[i][3]);
    if (BIAS) { v.x += bias4.x; v.y += bias4.y; v.z += bias4.z; v.w += bias4.w; }
    if (ACCUM) { float4 o = *(const float4*)cp; v.x += o.x; v.y += o.y; v.z += o.z; v.w += o.w; }
    if (RELU) { v.x = fmaxf(v.x, 0.f); v.y = fmaxf(v.y, 0.f); v.z = fmaxf(v.z, 0.f); v.w = fmaxf(v.w, 0.f); }
    *(float4*)cp = v;
  }
}

// ---------------- gemm128x64: 128x64 tile, 8x4 acc ----------------
template<bool BIAS>
__global__ __launch_bounds__(256) void gemm128x64(
    const float* __restrict__ A, int lda,
    const float* __restrict__ B, int ldb,
    float* __restrict__ C, int ldc,
    const float* __restrict__ bias,
    int M, int N, int K) {
  __shared__ float As[16][132];
  __shared__ float Bs[16][68];
  const int tid = threadIdx.x;
  const int n0 = blockIdx.x * 64, m0 = blockIdx.y * 128;
  const int tx = tid & 15, ty = tid >> 4;
  const int am = tid >> 1, ak = (tid & 1) << 3;   // A: row am, 8 k's
  const int bk = tid >> 4, bn = (tid & 15) << 2;  // B: row bk, 4 n's
  float acc[8][4] = {};
  for (int k0 = 0; k0 < K; k0 += 16) {
    {
      const float* ap = A + (size_t)(m0 + am) * lda + k0 + ak;
      float a0[8];
      if (k0 + ak + 7 < K) {
        float4 v0 = *(const float4*)ap, v1 = *(const float4*)(ap + 4);
        a0[0] = v0.x; a0[1] = v0.y; a0[2] = v0.z; a0[3] = v0.w;
        a0[4] = v1.x; a0[5] = v1.y; a0[6] = v1.z; a0[7] = v1.w;
      } else {
        #pragma unroll
        for (int i = 0; i < 8; i++) { int k = k0 + ak + i; a0[i] = (k < K) ? ap[i] : 0.f; }
      }
      #pragma unroll
      for (int i = 0; i < 8; i++) As[ak + i][am] = a0[i];
    }
    {
      float4 bv = make_float4(0.f, 0.f, 0.f, 0.f);
      int k = k0 + bk;
      if (k < K) bv = *(const float4*)(B + (size_t)k * ldb + n0 + bn);
      *(float4*)&Bs[bk][bn] = bv;
    }
    __syncthreads();
    #pragma unroll
    for (int kk = 0; kk < 16; kk++) {
      float4 a0 = *(const float4*)&As[kk][ty << 3];
      float4 a1 = *(const float4*)&As[kk][(ty << 3) + 4];
      float4 b = *(const float4*)&Bs[kk][tx << 2];
      float av[8] = {a0.x, a0.y, a0.z, a0.w, a1.x, a1.y, a1.z, a1.w};
      #pragma unroll
      for (int i = 0; i < 8; i++) {
        acc[i][0] = fmaf(av[i], b.x, acc[i][0]);
        acc[i][1] = fmaf(av[i], b.y, acc[i][1]);
        acc[i][2] = fmaf(av[i], b.z, acc[i][2]);
        acc[i][3] = fmaf(av[i], b.w, acc[i][3]);
      }
    }
    __syncthreads();
  }
  float4 bias4 = make_float4(0.f, 0.f, 0.f, 0.f);
  if (BIAS) bias4 = *(const float4*)(bias + n0 + (tx << 2));
  #pragma unroll
  for (int i = 0; i < 8; i++) {
    float* cp = C + (size_t)(m0 + (ty << 3) + i) * ldc + n0 + (tx << 2);
    float4 v = make_float4(acc[i][0], acc[i][1], acc[i][2], acc[i][3]);
    if (BIAS) { v.x += bias4.x; v.y += bias4.y; v.z += bias4.z; v.w += bias4.w; }
    *(float4*)cp = v;
  }
}

// ---------------- gemm64_dual: C = relu(A1@B[0:256] + A2@B[256:512] + bias) ----------------
__global__ __launch_bounds__(256) void gemm64_dual(
    const float* __restrict__ A1, const float* __restrict__ A2, int lda,  // both [M,256]
    const float* __restrict__ B, int ldb,    // [512, N]
    float* __restrict__ C, int ldc,
    const float* __restrict__ bias,
    int M, int N) {
  const int K = 512, KH = 256;
  __shared__ float As[16][68];
  __shared__ float Bs[16][68];
  const int tid = threadIdx.x;
  const int n0 = blockIdx.x * 64, m0 = blockIdx.y * 64;
  const int tx = tid & 15, ty = tid >> 4;
  const int am = tid >> 2, ak = (tid & 3) << 2;
  const int bk = tid >> 4, bn = (tid & 15) << 2;
  float acc[4][4] = {};
  for (int k0 = 0; k0 < K; k0 += 16) {
    int k = k0 + ak;
    const float* Arow = (k < KH) ? (A1 + (size_t)(m0 + am) * lda + k)
                                 : (A2 + (size_t)(m0 + am) * lda + (k - KH));
    float4 av = *(const float4*)Arow;
    As[ak + 0][am] = av.x; As[ak + 1][am] = av.y; As[ak + 2][am] = av.z; As[ak + 3][am] = av.w;
    float4 bv = *(const float4*)(B + (size_t)(k0 + bk) * ldb + n0 + bn);
    *(float4*)&Bs[bk][bn] = bv;
    __syncthreads();
    #pragma unroll
    for (int kk = 0; kk < 16; kk++) {
      float4 a = *(const float4*)&As[kk][ty << 2];
      float4 b = *(const float4*)&Bs[kk][tx << 2];
      acc[0][0] = fmaf(a.x, b.x, acc[0][0]); acc[0][1] = fmaf(a.x, b.y, acc[0][1]);
      acc[0][2] = fmaf(a.x, b.z, acc[0][2]); acc[0][3] = fmaf(a.x, b.w, acc[0][3]);
      acc[1][0] = fmaf(a.y, b.x, acc[1][0]); acc[1][1] = fmaf(a.y, b.y, acc[1][1]);
      acc[1][2] = fmaf(a.y, b.z, acc[1][2]); acc[1][3] = fmaf(a.y, b.w, acc[1][3]);
      acc[2][0] = fmaf(a.z, b.x, acc[2][0]); acc[2][1] = fmaf(a.z, b.y, acc[2][1]);
      acc[2][2] = fmaf(a.z, b.z, acc[2][2]); acc[2][3] = fmaf(a.z, b.w, acc[2][3]);
      acc[3][0] = fmaf(a.w, b.x, acc[3][0]); acc[3][1] = fmaf(a.w, b.y, acc[3][1]);
      acc[3][2] = fmaf(a.w, b.z, acc[3][2]); acc[3][3] = fmaf(a.w, b.w, acc[3][3]);
    }
    __syncthreads();
  }
  float4 bias4 = *(const float4*)(bias + n0 + (tx << 2));
  #pragma unroll
  for (int i = 0; i < 4; i++) {
    float* cp = C + (size_t)(m0 + (ty << 2) + i) * ldc + n0 + (tx << 2);
    float4 v = make_float4(acc[i][0] + bias4.x, acc[i][1] + bias4.y,
                           acc[i][2] + bias4.z, acc[i][3] + bias4.w);
    v.x = fmaxf(v.x, 0.f); v.y = fmaxf(v.y, 0.f); v.z = fmaxf(v.z, 0.f); v.w = fmaxf(v.w, 0.f);
    *(float4*)cp = v;
  }
}

// ---------------- GRU recurrence v13-final (best measured: 373.8 us) ----------------
// 64 blocks = (dir,doc), 512 threads: thread = (row j = t>>2, quarter q = t&3),
// 96 weights parked in a0..a95 (outside RA's domain -> unspillable),
// accvgpr_read bounce, DPP quad butterfly, swizzled dbuf h, lgkm-only barrier.
// Structural floor ~1750 cyc/step: exposed serial chain with 2 waves/SIMD
// (register-file-capped: 80 VGPR + 96 AGPR). v10/v14 (4 waves, 8-way split)
// both regressed ~35% from redundant per-lane activation overhead.
#define SWZ(k) ((k) + 4 * ((k) >> 4))
#define BAR_LGKM() asm volatile("s_waitcnt lgkmcnt(0)\n\ts_barrier" ::: "memory")

#define QADD(X, CTRL) do { \
    int _t = __builtin_amdgcn_update_dpp(0, __float_as_int(X), CTRL, 0xF, 0xF, true); \
    X += __int_as_float(_t); } while (0)
// quad_perm [1,0,3,2] = 0xB1 (xor1) ; [2,3,0,1] = 0x4E (xor2)

#define AW(N, V) asm volatile("v_accvgpr_write_b32 a" #N ", %0" :: "v"(V) : "a" #N)
#define AWQ(N0, N1, N2, N3, Q) do { AW(N0, (Q).x); AW(N1, (Q).y); AW(N2, (Q).z); AW(N3, (Q).w); } while (0)

#define A96CLOB \
  "a0","a1","a2","a3","a4","a5","a6","a7","a8","a9","a10","a11","a12","a13","a14","a15", \
  "a16","a17","a18","a19","a20","a21","a22","a23","a24","a25","a26","a27","a28","a29","a30","a31", \
  "a32","a33","a34","a35","a36","a37","a38","a39","a40","a41","a42","a43","a44","a45","a46","a47", \
  "a48","a49","a50","a51","a52","a53","a54","a55","a56","a57","a58","a59","a60","a61","a62","a63", \
  "a64","a65","a66","a67","a68","a69","a70","a71","a72","a73","a74","a75","a76","a77","a78","a79", \
  "a80","a81","a82","a83","a84","a85","a86","a87","a88","a89","a90","a91","a92","a93","a94","a95"

#define RD(T, N) "v_accvgpr_read_b32 %[" #T "], a" #N "\n\t"
#define FM(P, T, X) "v_fmac_f32 %[" #P "], %[" #T "], %[" #X "]\n\t"
#define COLA(CR, CZ, CN, X) \
  RD(t0, CR) RD(t1, CZ) RD(t2, CN) FM(pr, t0, X) FM(pz, t1, X) FM(pn, t2, X)

__global__ __launch_bounds__(512, 2) void gru_kernel(
    const float* __restrict__ gxbuf,   // [M,768] : row b*512+s, cols [dir*384 + gate*128 + j]
    const float* __restrict__ Whh_f, const float* __restrict__ Whh_b,
    const float* __restrict__ bhh_f, const float* __restrict__ bhh_b,
    float* __restrict__ sent_rep,      // [B,S,256]
    float* __restrict__ last_f, float* __restrict__ last_b) {
  const int bid = blockIdx.x;          // 64 = dir*32 + b
  const int dir = bid >> 5, b = bid & 31;
  const int t = threadIdx.x;           // 0..511
  const int j = t >> 2;                // row 0..127
  const int q = t & 3;                 // k-quarter 0..3 (32 cols each)
  const int k0 = q << 5;
  const float* Whh = dir ? Whh_b : Whh_f;
  const float* bhh = dir ? bhh_b : bhh_f;

  // ---- load 96 weight floats and park them in a0..a95 ----
  {
    const float* Wr = Whh + (size_t)j * 128 + k0;
    const float* Wz = Whh + (size_t)(128 + j) * 128 + k0;
    const float* Wn = Whh + (size_t)(256 + j) * 128 + k0;
    f32x4 w0 = *(const f32x4*)(Wr + 0),  w1 = *(const f32x4*)(Wr + 4);
    f32x4 w2 = *(const f32x4*)(Wr + 8),  w3 = *(const f32x4*)(Wr + 12);
    f32x4 w4 = *(const f32x4*)(Wr + 16), w5 = *(const f32x4*)(Wr + 20);
    f32x4 w6 = *(const f32x4*)(Wr + 24), w7 = *(const f32x4*)(Wr + 28);
    AWQ(0, 1, 2, 3, w0);   AWQ(4, 5, 6, 7, w1);   AWQ(8, 9, 10, 11, w2);  AWQ(12, 13, 14, 15, w3);
    AWQ(16, 17, 18, 19, w4); AWQ(20, 21, 22, 23, w5); AWQ(24, 25, 26, 27, w6); AWQ(28, 29, 30, 31, w7);
    w0 = *(const f32x4*)(Wz + 0);  w1 = *(const f32x4*)(Wz + 4);
    w2 = *(const f32x4*)(Wz + 8);  w3 = *(const f32x4*)(Wz + 12);
    w4 = *(const f32x4*)(Wz + 16); w5 = *(const f32x4*)(Wz + 20);
    w6 = *(const f32x4*)(Wz + 24); w7 = *(const f32x4*)(Wz + 28);
    AWQ(32, 33, 34, 35, w0); AWQ(36, 37, 38, 39, w1); AWQ(40, 41, 42, 43, w2); AWQ(44, 45, 46, 47, w3);
    AWQ(48, 49, 50, 51, w4); AWQ(52, 53, 54, 55, w5); AWQ(56, 57, 58, 59, w6); AWQ(60, 61, 62, 63, w7);
    w0 = *(const f32x4*)(Wn + 0);  w1 = *(const f32x4*)(Wn + 4);
    w2 = *(const f32x4*)(Wn + 8);  w3 = *(const f32x4*)(Wn + 12);
    w4 = *(const f32x4*)(Wn + 16); w5 = *(const f32x4*)(Wn + 20);
    w6 = *(const f32x4*)(Wn + 24); w7 = *(const f32x4*)(Wn + 28);
    AWQ(64, 65, 66, 67, w0); AWQ(68, 69, 70, 71, w1); AWQ(72, 73, 74, 75, w2); AWQ(76, 77, 78, 79, w3);
    AWQ(80, 81, 82, 83, w4); AWQ(84, 85, 86, 87, w5); AWQ(88, 89, 90, 91, w6); AWQ(92, 93, 94, 95, w7);
  }

  // per-lane bias folds (q==0 lane carries all three; summed by the butterfly)
  const float cR = (q == 0) ? bhh[j] : 0.f;
  const float cZ = (q == 0) ? bhh[128 + j] : 0.f;
  const float cN = (q == 0) ? bhh[256 + j] : 0.f;
  // gx gate for this lane: q1->r, q2->z, q0/q3->n (q0 uses gx_c as gn directly)
  const int gate = (q == 1) ? 0 : (q == 2) ? 1 : 2;
  const float mr = (q == 1) ? 1.f : 0.f;
  const float mz = (q == 2) ? 1.f : 0.f;

  __shared__ float lds[320];           // 2 x 160-word swizzled h buffers
  if (t < 128) lds[SWZ(t)] = 0.f;
  __syncthreads();

  const int stp = dir ? -1 : 1;
  const int ts0 = dir ? 511 : 0;
  const ptrdiff_t g768 = (ptrdiff_t)stp * 768;
  const ptrdiff_t s256 = (ptrdiff_t)stp * 256;
  const float* gq = gxbuf + (size_t)b * 512 * 768 + dir * 384 + gate * 128 + j + (size_t)ts0 * 768;
  float* sp = sent_rep + (size_t)b * 512 * 256 + dir * 128 + (size_t)ts0 * 256;
  float hprev = 0.f;
  float gx_c = gq[0];
  float gx_1 = gq[g768];

#define GRU_STEP(P, SOFF) do { \
    float gx_2 = 0.f; \
    if (s + 2 + (SOFF) < 512) gx_2 = gq[2 * g768]; \
    const f32x4* hv = (const f32x4*)(lds + (P) * 160 + 40 * q); \
    f32x4 h0 = hv[0], h1 = hv[1], h2 = hv[2], h3 = hv[3]; \
    f32x4 h4 = hv[5], h5 = hv[6], h6 = hv[7], h7 = hv[8]; \
    float pr = cR, pz = cZ, pn = cN; \
    { float t0v, t1v, t2v; \
      asm volatile( \
        COLA(0,32,64,x0)   COLA(1,33,65,x1)   COLA(2,34,66,x2)   COLA(3,35,67,x3) \
        COLA(4,36,68,x4)   COLA(5,37,69,x5)   COLA(6,38,70,x6)   COLA(7,39,71,x7) \
        COLA(8,40,72,x8)   COLA(9,41,73,x9)   COLA(10,42,74,x10) COLA(11,43,75,x11) \
        COLA(12,44,76,x12) COLA(13,45,77,x13) COLA(14,46,78,x14) COLA(15,47,79,x15) \
        : [pr]"+v"(pr), [pz]"+v"(pz), [pn]"+v"(pn), \
          [t0]"=&v"(t0v), [t1]"=&v"(t1v), [t2]"=&v"(t2v) \
        : [x0]"v"(h0.x), [x1]"v"(h0.y), [x2]"v"(h0.z), [x3]"v"(h0.w), \
          [x4]"v"(h1.x), [x5]"v"(h1.y), [x6]"v"(h1.z), [x7]"v"(h1.w), \
          [x8]"v"(h2.x), [x9]"v"(h2.y), [x10]"v"(h2.z), [x11]"v"(h2.w), \
          [x12]"v"(h3.x), [x13]"v"(h3.y), [x14]"v"(h3.z), [x15]"v"(h3.w) \
        : A96CLOB); \
      asm volatile( \
        COLA(16,48,80,x0)  COLA(17,49,81,x1)  COLA(18,50,82,x2)  COLA(19,51,83,x3) \
        COLA(20,52,84,x4)  COLA(21,53,85,x5)  COLA(22,54,86,x6)  COLA(23,55,87,x7) \
        COLA(24,56,88,x8)  COLA(25,57,89,x9)  COLA(26,58,90,x10) COLA(27,59,91,x11) \
        COLA(28,60,92,x12) COLA(29,61,93,x13) COLA(30,62,94,x14) COLA(31,63,95,x15) \
        : [pr]"+v"(pr), [pz]"+v"(pz), [pn]"+v"(pn), \
          [t0]"=&v"(t0v), [t1]"=&v"(t1v), [t2]"=&v"(t2v) \
        : [x0]"v"(h4.x), [x1]"v"(h4.y), [x2]"v"(h4.z), [x3]"v"(h4.w), \
          [x4]"v"(h5.x), [x5]"v"(h5.y), [x6]"v"(h5.z), [x7]"v"(h5.w), \
          [x8]"v"(h6.x), [x9]"v"(h6.y), [x10]"v"(h6.z), [x11]"v"(h6.w), \
          [x12]"v"(h7.x), [x13]"v"(h7.y), [x14]"v"(h7.z), [x15]"v"(h7.w) \
        : A96CLOB); } \
    pr = fmaf(mr, gx_c, pr); \
    pz = fmaf(mz, gx_c, pz); \
    QADD(pr, 0xB1); QADD(pr, 0x4E); \
    QADD(pz, 0xB1); QADD(pz, 0x4E); \
    QADD(pn, 0xB1); QADD(pn, 0x4E); \
    float xr = fminf(fmaxf(pr, -30.f), 30.f); \
    float xz = fminf(fmaxf(pz, -30.f), 30.f); \
    float r = 1.f / (1.f + __expf(-xr)); \
    float z = 1.f / (1.f + __expf(-xz)); \
    float xn = gx_c + r * pn; xn = fminf(fmaxf(xn, -15.f), 15.f); \
    float e2 = __expf(2.f * xn); \
    float n = (e2 - 1.f) / (e2 + 1.f); \
    float hnew = (1.f - z) * n + z * hprev; \
    hprev = hnew; \
    if (q == 0) { \
      lds[((P) ^ 1) * 160 + SWZ(j)] = hnew; \
      sp[j] = hnew; \
    } \
    BAR_LGKM(); \
    gq += g768; sp += s256; \
    gx_c = gx_1; gx_1 = gx_2; \
  } while (0)

  #pragma unroll 1
  for (int s = 0; s < 512; s += 2) {
    GRU_STEP(0, 0);
    GRU_STEP(1, 1);
  }
#undef GRU_STEP

  if (q == 0) (dir ? last_b : last_f)[b * 128 + j] = hprev;
}

// ---------------- fused misc: topicmat (blocks 0..511) + docvec (512..543) + seg (544..607) ----------------
__global__ void misc_kernel(const float* __restrict__ sent_rep, const int* __restrict__ tse,
                            const float* __restrict__ last_f, const float* __restrict__ last_b,
                            float* __restrict__ topic_mat, float* __restrict__ doc_vec,
                            int* __restrict__ seg) {
  int blk = blockIdx.x;
  if (blk < 512) {
    int b = blk >> 4, t = blk & 15;
    int st = tse[(b * 16 + t) * 2 + 0];   // 1-based
    int en = tse[(b * 16 + t) * 2 + 1];
    int jj = threadIdx.x;                 // 0..255
    const float* sr = sent_rep + (size_t)b * 512 * 256;
    float val;
    if (jj < 128) {
      float a = sr[(size_t)(en - 1) * 256 + jj];
      float c = (st - 2 >= 0) ? sr[(size_t)(st - 2) * 256 + jj] : 0.f;
      val = a - c;
    } else {
      float a = sr[(size_t)(st - 1) * 256 + jj];
      float c = (en <= 511) ? sr[(size_t)en * 256 + jj] : 0.f;
      val = a - c;
    }
    topic_mat[(size_t)blk * 256 + jj] = val;
  } else if (blk < 544) {
    int idx = (blk - 512) * 256 + threadIdx.x;  // 8192
    int i = idx >> 8, c = idx & 255;
    const float* src = (i < 16) ? last_f : last_b;
    int ii = (i < 16) ? i : i - 16;
    int bb = 2 * ii + (c >> 7);
    doc_vec[idx] = src[bb * 128 + (c & 127)];
  } else {
    int idx = (blk - 544) * 256 + threadIdx.x;  // 16384
    int b = idx >> 9, s = idx & 511;
    int pos = s + 1, cnt = 0;
    for (int t = 0; t < T_; t++) cnt += (tse[(b * T_ + t) * 2] <= pos);
    int sg = cnt - 1; sg = sg < 0 ? 0 : (sg > T_ - 1 ? T_ - 1 : sg);
    seg[idx] = sg;
  }
}

// ---------------- scores + ratios + context (wave per row) ----------------
__global__ void scores_ctx_kernel(const float* __restrict__ sr_part,     // [M,512]
                                  const float* __restrict__ doc_part,    // [32,512]
                                  const float* __restrict__ topic_part,  // [32,16,512]
                                  const float* __restrict__ v_att,       // [512]
                                  const float* __restrict__ doc_vec,     // [32,256]
                                  const float* __restrict__ topic_mat,   // [32,16,256]
                                  const int* __restrict__ seg,           // [M]
                                  float* __restrict__ context) {         // [M,256]
  int wid = threadIdx.x >> 6, lane = threadIdx.x & 63;
  int row = blockIdx.x * 4 + wid;
  int b = row >> 9;
  int sg = seg[row];
  const float* srp = sr_part + (size_t)row * 512;
  const float* dp = doc_part + (size_t)b * 512;
  const float* tp = topic_part + (size_t)(b * 16 + sg) * 512;
  float accd = 0.f, acct = 0.f;
  #pragma unroll
  for (int i = 0; i < 8; i++) {
    int n = lane + i * 64;
    float sp = srp[n], va = v_att[n];
    accd += tanhf(dp[n] + sp) * va;
    acct += tanhf(tp[n] + sp) * va;
  }
  #pragma unroll
  for (int off = 32; off; off >>= 1) { accd += __shfl_xor(accd, off); acct += __shfl_xor(acct, off); }
  float ssum = accd + acct;
  float rd = accd / ssum, rt = acct / ssum;
  const float* dv = doc_vec + (size_t)b * 256;
  const float* tm = topic_mat + (size_t)(b * 16 + sg) * 256;
  float* ctx = context + (size_t)row * 256;
  #pragma unroll
  for (int i = 0; i < 4; i++) {
    int jj = lane + i * 64;
    ctx[jj] = rd * dv[jj] + rt * tm[jj];
  }
}

// ---------------- logits: out = h . W2 + b2 (wave per row) ----------------
__global__ void logits_kernel(const float* __restrict__ h, const float* __restrict__ W2,
                              const float* __restrict__ b2, float* __restrict__ out, int M) {
  int wid = threadIdx.x >> 6, lane = threadIdx.x & 63;
  int row = blockIdx.x * 4 + wid;
  if (row >= M) return;
  const float* hp = h + (size_t)row * 128;
  float s = hp[lane] * W2[lane] + hp[lane + 64] * W2[lane + 64];
  #pragma unroll
  for (int off = 32; off; off >>= 1) s += __shfl_xor(s, off);
  if (lane == 0) out[row] = s + b2[0];
}

extern "C" void kernel_launch(void* const* d_in, const int* in_sizes, int n_in,
                              void* d_out, int out_size, void* d_ws, size_t ws_size,
                              hipStream_t stream) {
  const int*   word_ids = (const int*)d_in[0];
  const int*   tse      = (const int*)d_in[1];
  const float* emb      = (const float*)d_in[2];
  const float* Wih_f    = (const float*)d_in[3];
  const float* Whh_f    = (const float*)d_in[4];
  const float* bih_f    = (const float*)d_in[5];
  const float* bhh_f    = (const float*)d_in[6];
  const float* Wih_b    = (const float*)d_in[7];
  const float* Whh_b    = (const float*)d_in[8];
  const float* bih_b    = (const float*)d_in[9];
  const float* bhh_b    = (const float*)d_in[10];
  const float* W_att    = (const float*)d_in[11];
  const float* v_att    = (const float*)d_in[12];
  const float* W1       = (const float*)d_in[13];
  const float* b1       = (const float*)d_in[14];
  const float* W2       = (const float*)d_in[15];
  const float* b2       = (const float*)d_in[16];
  float* ws  = (float*)d_ws;
  float* out = (float*)d_out;

  prep_kernel<<<900, 256, 0, stream>>>(Wih_f, Wih_b, bih_f, bih_b, W1,
                                       ws + OFF_WTIH, ws + OFF_BIASIH, ws + OFF_W1T);
  embed_mean_kernel<<<M_ / 4, 256, 0, stream>>>(word_ids, emb, ws + OFF_X);
  // gx = x @ [Wih_f|Wih_b]^T + bias  -> [M,768]
  gemm128x64<true><<<dim3(12, 128), 256, 0, stream>>>(
      ws + OFF_X, E_, ws + OFF_WTIH, 768, ws + OFF_GX, 768, ws + OFF_BIASIH, M_, 768, E_);
  gru_kernel<<<64, 512, 0, stream>>>(ws + OFF_GX, Whh_f, Whh_b, bhh_f, bhh_b,
                                     ws + OFF_SENT, ws + OFF_LASTF, ws + OFF_LASTB);
  // fused: topicmat + docvec + seg
  misc_kernel<<<608, 256, 0, stream>>>(ws + OFF_SENT, tse, ws + OFF_LASTF, ws + OFF_LASTB,
                                       ws + OFF_TOPICMAT, ws + OFF_DOCVEC, (int*)(ws + OFF_SEG));
  // doc_part = doc_vec @ W_att[0:256,:]
  gemm64<false, false, false><<<dim3(8, 1), 256, 0, stream>>>(
      ws + OFF_DOCVEC, 256, W_att, 512, ws + OFF_DOCPART, 512, nullptr, 32, 512, 256);
  // topic_part = topic_mat @ W_att[0:256,:]   (M=512 -> 4 row-blocks)
  gemm128x64<false><<<dim3(8, 4), 256, 0, stream>>>(
      ws + OFF_TOPICMAT, 256, W_att, 512, ws + OFF_TOPICPART, 512, nullptr, 512, 512, 256);
  // sr_part = sent_rep @ W_att[256:512,:]
  gemm128x64<false><<<dim3(8, 128), 256, 0, stream>>>(
      ws + OFF_SENT, 256, W_att + 256 * 512, 512, ws + OFF_SRPART, 512, nullptr, M_, 512, 256);
  scores_ctx_kernel<<<M_ / 4, 256, 0, stream>>>(
      ws + OFF_SRPART, ws + OFF_DOCPART, ws + OFF_TOPICPART, v_att,
      ws + OFF_DOCVEC, ws + OFF_TOPICMAT, (const int*)(ws + OFF_SEG), ws + OFF_CTX);
  // h = relu(sent_rep @ W1t[0:256] + context @ W1t[256:512] + b1)  (fused dual GEMM)
  gemm64_dual<<<dim3(2, 256), 256, 0, stream>>>(
      ws + OFF_SENT, ws + OFF_CTX, 256, ws + OFF_W1T, 128, ws + OFF_H, 128, b1, M_, 128);
  logits_kernel<<<M_ / 4, 256, 0, stream>>>(ws + OFF_H, W2, b2, out, M_);
}